// Round 1
// 253.392 us; speedup vs baseline: 1.0009x; 1.0009x over previous
//
#include <hip/hip_runtime.h>
#include <math.h>

// EnergySRB, R6: occupancy doubling.
// R5 was latency-bound: LDS_Block_Size=82944B -> 1 block/CU -> 16 waves/CU
// (Occupancy 37%), with VALUBusy 20%, HBM 16%, MFMA 0 - nothing saturated.
// R6 trims per-block LDS to EXACTLY 80KB (64KB packed species + 16KB u32
// bins) so TWO 1024-thread blocks co-reside per CU (2x80KB = 160KB = full
// LDS, 32 waves/CU). The 16-entry (|pre|,dfac) table moves from LDS into
// wave registers: lane L holds tab[L&15]; per-pair lookup is two
// __shfl(val, idx) (ds_bpermute crossbar - no LDS storage, no bank
// conflicts). Grid 256 -> 512 blocks (2/CU, exactly 4 iters/thread).

#define NT        1024
#define NBLK      512
#define SCALE_F   134217728.0f              // 2^27
#define INV_SCALE 7.450580596923828125e-9   // 2^-27, exact in double

// ---------------------------------------------------------------------------
// pack species (values 0..3) into 2-bit words. 262144 atoms -> 64KB.
__global__ void pack_species_kernel(const int* __restrict__ sp,
                                    unsigned* __restrict__ packed, int nwords) {
    int w = blockIdx.x * blockDim.x + threadIdx.x;
    if (w >= nwords) return;
    const int4* p4 = (const int4*)(sp + (w << 4));
    int4 a = p4[0], b = p4[1], c = p4[2], d = p4[3];
    unsigned v =
        (unsigned)(a.x & 3)        | ((unsigned)(a.y & 3) << 2)  |
        ((unsigned)(a.z & 3) << 4) | ((unsigned)(a.w & 3) << 6)  |
        ((unsigned)(b.x & 3) << 8) | ((unsigned)(b.y & 3) << 10) |
        ((unsigned)(b.z & 3) << 12)| ((unsigned)(b.w & 3) << 14) |
        ((unsigned)(c.x & 3) << 16)| ((unsigned)(c.y & 3) << 18) |
        ((unsigned)(c.z & 3) << 20)| ((unsigned)(c.w & 3) << 22) |
        ((unsigned)(d.x & 3) << 24)| ((unsigned)(d.y & 3) << 26) |
        ((unsigned)(d.z & 3) << 28)| ((unsigned)(d.w & 3) << 30);
    packed[w] = v;
}

// ---------------------------------------------------------------------------
// init: species passthrough to out[0:n_species); zero the u64 accumulator.
__global__ void init_kernel(const int* __restrict__ species,
                            float* __restrict__ out,
                            unsigned long long* __restrict__ acc,
                            int n_species, int n_mol) {
    int i = blockIdx.x * blockDim.x + threadIdx.x;
    if (i < n_species) out[i] = (float)species[i];
    if (i < n_mol)     acc[i] = 0ull;
}

// ---------------------------------------------------------------------------
// Fused main kernel. LDS: exactly 80KB = 64KB packed species + 16KB u32 bins.
// Table lives in wave registers, looked up via __shfl (ds_bpermute).
__global__ __launch_bounds__(NT, 8)
void srb_fused_u32(const unsigned* __restrict__ packed_ws,
                   const int* __restrict__ ai,     // [2, P]
                   const float* __restrict__ dist, // [P] angstrom
                   const float* __restrict__ pre_tab,   // 16 floats (negative)
                   const float* __restrict__ dfac_tab,  // 16 floats
                   unsigned long long* __restrict__ acc, // [n_mol]
                   int P, int mol_shift) {
    __shared__ unsigned packed[16384]; // 64KB: 2-bit species, all atoms
    __shared__ unsigned binsu[4096];   // 16KB: fixed-point per-mol sums

    const int t = threadIdx.x;
    for (int i = t; i < 4096; i += NT) binsu[i] = 0u;

    // register-resident table: lane L (of each wave) holds entry L&15.
    const float myPre  = -pre_tab[t & 15];   // magnitude, > 0
    const float myDfac =  dfac_tab[t & 15];

    {
        int4* dst = (int4*)packed;
        const int4* src = (const int4*)packed_ws;
        for (int i = t; i < 4096; i += NT) dst[i] = src[i];
    }
    __syncthreads();

    const float a2b   = (float)1.8897261258369282;
    const float rc    = (float)(5.2 * 1.8897261258369282);
    const float rcinv = (float)(1.0 / (5.2 * 1.8897261258369282));

    // 8 pairs per iteration; all loads per thread contiguous (32B rows).
    const int ng     = P >> 3;                 // groups of 8
    const int stride = (int)gridDim.x * NT;
    const int4*   v0 = (const int4*)ai;
    const int4*   v1 = (const int4*)(ai + P);
    const float4* dv = (const float4*)dist;

    for (int g = (int)blockIdx.x * NT + t; g < ng; g += stride) {
        int4   i0a = v0[2 * g], i0b = v0[2 * g + 1];
        int4   i1a = v1[2 * g], i1b = v1[2 * g + 1];
        float4 da  = dv[2 * g], db4 = dv[2 * g + 1];

        unsigned a0[8] = { (unsigned)i0a.x, (unsigned)i0a.y, (unsigned)i0a.z,
                           (unsigned)i0a.w, (unsigned)i0b.x, (unsigned)i0b.y,
                           (unsigned)i0b.z, (unsigned)i0b.w };
        unsigned a1[8] = { (unsigned)i1a.x, (unsigned)i1a.y, (unsigned)i1a.z,
                           (unsigned)i1a.w, (unsigned)i1b.x, (unsigned)i1b.y,
                           (unsigned)i1b.z, (unsigned)i1b.w };
        float    dd[8] = { da.x, da.y, da.z, da.w, db4.x, db4.y, db4.z, db4.w };

        // Phase 1: all 16 species gathers in flight.
        unsigned w0[8], w1[8];
        #pragma unroll
        for (int k = 0; k < 8; ++k) w0[k] = packed[a0[k] >> 4];
        #pragma unroll
        for (int k = 0; k < 8; ++k) w1[k] = packed[a1[k] >> 4];

        // Phase 2: table lookup via wave shuffle (ds_bpermute, conflict-free).
        float pr[8], df[8];
        #pragma unroll
        for (int k = 0; k < 8; ++k) {
            unsigned s0 = (w0[k] >> ((a0[k] & 15u) << 1)) & 3u;
            unsigned s1 = (w1[k] >> ((a1[k] & 15u) << 1)) & 3u;
            int idx = (int)((s0 << 2) | s1);
            pr[k] = __shfl(myPre,  idx, 64);
            df[k] = __shfl(myDfac, idx, 64);
        }

        // Phase 3: 8 independent VALU chains.
        unsigned q[8];
        #pragma unroll
        for (int k = 0; k < 8; ++k) {
            float db  = dd[k] * a2b;
            float x   = db * rcinv;
            float arg = df[k] * db + (1.0f - 1.0f / (1.0f - x * x));
            float mag = pr[k] * __expf(arg);     // pr = |pre| > 0
            mag = (db < rc) ? mag : 0.0f;        // exact 0 beyond cutoff
            q[k] = (unsigned)(mag * SCALE_F);    // trunc; < 2^24 always
        }

        // Phase 4: 8 branchless atomics (q==0 adds zero; still one BB).
        #pragma unroll
        for (int k = 0; k < 8; ++k)
            atomicAdd(&binsu[a0[k] >> mol_shift], q[k]); // native ds_add_u32
    }

    __syncthreads();
    for (int i = t; i < 4096; i += NT) {
        unsigned v = binsu[i];
        if (v) atomicAdd(&acc[i], (unsigned long long)v); // native u64 atomic
    }
}

// ---------------------------------------------------------------------------
// final: out_e[m] = energies[m] - acc[m] * 2^-27  (exact in double)
__global__ void final_kernel(const unsigned long long* __restrict__ acc,
                             const float* __restrict__ energies,
                             float* __restrict__ out_e, int n_mol) {
    int m = blockIdx.x * blockDim.x + threadIdx.x;
    if (m < n_mol)
        out_e[m] = energies[m] - (float)((double)acc[m] * INV_SCALE);
}

// ---------------------------------------------------------------------------
// Fallback (ws too small): fused float-atomic path, out_e preset.
__global__ void init_out_fallback(const int* __restrict__ species,
                                  const float* __restrict__ energies,
                                  float* __restrict__ out,
                                  int n_species, int n_mol) {
    int i = blockIdx.x * blockDim.x + threadIdx.x;
    if (i < n_species) out[i] = (float)species[i];
    else if (i < n_species + n_mol) out[i] = energies[i - n_species];
}

__global__ __launch_bounds__(NT, 1)
void srb_fused_f32(const int* __restrict__ species,
                   const int* __restrict__ ai,
                   const float* __restrict__ dist,
                   const float* __restrict__ pre_tab,
                   const float* __restrict__ dfac_tab,
                   float* __restrict__ out_e,
                   int P, int mol_shift) {
    __shared__ unsigned packed[16384];
    __shared__ float bins[4096];
    __shared__ float2 tab[16];
    const int t = threadIdx.x;
    for (int i = t; i < 4096; i += NT) bins[i] = 0.0f;
    if (t < 16) tab[t] = make_float2(pre_tab[t], dfac_tab[t]);
    for (int w = t; w < 16384; w += NT) {
        const int4* p4 = (const int4*)(species + (w << 4));
        int4 a = p4[0], b = p4[1], c = p4[2], d = p4[3];
        unsigned v =
            (unsigned)(a.x & 3)        | ((unsigned)(a.y & 3) << 2)  |
            ((unsigned)(a.z & 3) << 4) | ((unsigned)(a.w & 3) << 6)  |
            ((unsigned)(b.x & 3) << 8) | ((unsigned)(b.y & 3) << 10) |
            ((unsigned)(b.z & 3) << 12)| ((unsigned)(b.w & 3) << 14) |
            ((unsigned)(c.x & 3) << 16)| ((unsigned)(c.y & 3) << 18) |
            ((unsigned)(c.z & 3) << 20)| ((unsigned)(c.w & 3) << 22) |
            ((unsigned)(d.x & 3) << 24)| ((unsigned)(d.y & 3) << 26) |
            ((unsigned)(d.z & 3) << 28)| ((unsigned)(d.w & 3) << 30);
        packed[w] = v;
    }
    __syncthreads();
    const float a2b   = (float)1.8897261258369282;
    const float rc    = (float)(5.2 * 1.8897261258369282);
    const float rcinv = (float)(1.0 / (5.2 * 1.8897261258369282));
    auto body = [&](int a0, int a1, float dang) {
        unsigned ua0 = (unsigned)a0, ua1 = (unsigned)a1;
        unsigned s0 = (packed[ua0 >> 4] >> ((ua0 & 15u) << 1)) & 3u;
        unsigned s1 = (packed[ua1 >> 4] >> ((ua1 & 15u) << 1)) & 3u;
        float2 td = tab[(s0 << 2) | s1];
        float db = dang * a2b;
        float x  = db * rcinv;
        float arg = td.y * db + (1.0f - 1.0f / (1.0f - x * x));
        float srb = td.x * __expf(arg);
        srb = (db < rc) ? srb : 0.0f;
        atomicAdd(&bins[ua0 >> mol_shift], srb);
    };
    const int nv = P >> 2, stride = (int)gridDim.x * NT;
    const int4* v0 = (const int4*)ai;
    const int4* v1 = (const int4*)(ai + P);
    const float4* dv = (const float4*)dist;
    for (int v = (int)blockIdx.x * NT + t; v < nv; v += stride) {
        int4 i0 = v0[v]; int4 i1 = v1[v]; float4 dd = dv[v];
        body(i0.x, i1.x, dd.x); body(i0.y, i1.y, dd.y);
        body(i0.z, i1.z, dd.z); body(i0.w, i1.w, dd.w);
    }
    __syncthreads();
    for (int i = t; i < 4096; i += NT) {
        float s = bins[i];
        if (s != 0.0f) atomicAdd(&out_e[i], s);
    }
}

// ---------------------------------------------------------------------------
extern "C" void kernel_launch(void* const* d_in, const int* in_sizes, int n_in,
                              void* d_out, int out_size, void* d_ws, size_t ws_size,
                              hipStream_t stream) {
    const int*   species  = (const int*)d_in[0];
    const float* energies = (const float*)d_in[1];
    const int*   ai       = (const int*)d_in[2];
    const float* dist     = (const float*)d_in[3];
    const float* pre_tab  = (const float*)d_in[4];
    const float* dfac_tab = (const float*)d_in[5];

    const int n_species = in_sizes[0];            // 262144
    const int n_mol     = in_sizes[1];            // 4096
    const int P         = in_sizes[3];            // 16777216
    const int n_atoms   = n_species / n_mol;      // 64

    int mol_shift = 0;
    while ((1 << mol_shift) < n_atoms) ++mol_shift; // 6

    float* out   = (float*)d_out;
    float* out_e = out + n_species;

    const int    nwords    = n_species / 16;              // 16384
    const size_t packed_sz = (size_t)nwords * 4;          // 64KB
    const size_t acc_sz    = (size_t)n_mol * 8;           // 32KB
    const size_t need      = packed_sz + acc_sz;

    if (ws_size >= need && (P & 7) == 0) {
        unsigned*           packed = (unsigned*)d_ws;
        unsigned long long* acc    = (unsigned long long*)((char*)d_ws + packed_sz);

        init_kernel<<<(n_species + 255) / 256, 256, 0, stream>>>(
            species, out, acc, n_species, n_mol);
        pack_species_kernel<<<(nwords + 255) / 256, 256, 0, stream>>>(
            species, packed, nwords);
        srb_fused_u32<<<NBLK, NT, 0, stream>>>(
            packed, ai, dist, pre_tab, dfac_tab, acc, P, mol_shift);
        final_kernel<<<(n_mol + 255) / 256, 256, 0, stream>>>(
            acc, energies, out_e, n_mol);
    } else {
        init_out_fallback<<<(n_species + n_mol + 255) / 256, 256, 0, stream>>>(
            species, energies, out, n_species, n_mol);
        srb_fused_f32<<<NBLK, NT, 0, stream>>>(
            species, ai, dist, pre_tab, dfac_tab, out_e, P, mol_shift);
    }
}

// Round 2
// 251.933 us; speedup vs baseline: 1.0067x; 1.0058x over previous
//
#include <hip/hip_runtime.h>
#include <math.h>

// EnergySRB, R7: restore ILP at 2-blocks/CU occupancy.
// R6 post-mortem: occupancy doubled (37->70%) but dur unchanged. Cause:
// __launch_bounds__(1024,8) made the compiler minimize to 28 VGPRs, which
// cannot hold the 8-pair phase structure (6x16B load buffers = 24 regs) ->
// phases re-serialized, per-wave ILP halved, cancelling the occupancy gain.
// R7: 4-pair groups (3x16B buffers) + explicit one-deep register prefetch
// (software pipeline). Next group's global loads are in flight while the
// current group computes; ~55 VGPRs fits the 64-VGPR ceiling of 8 waves/EU.
// Math is bit-identical to R6 (same op sequence) - absmax must not move.

#define NT        1024
#define NBLK      512
#define SCALE_F   134217728.0f              // 2^27
#define INV_SCALE 7.450580596923828125e-9   // 2^-27, exact in double

// ---------------------------------------------------------------------------
// pack species (values 0..3) into 2-bit words. 262144 atoms -> 64KB.
__global__ void pack_species_kernel(const int* __restrict__ sp,
                                    unsigned* __restrict__ packed, int nwords) {
    int w = blockIdx.x * blockDim.x + threadIdx.x;
    if (w >= nwords) return;
    const int4* p4 = (const int4*)(sp + (w << 4));
    int4 a = p4[0], b = p4[1], c = p4[2], d = p4[3];
    unsigned v =
        (unsigned)(a.x & 3)        | ((unsigned)(a.y & 3) << 2)  |
        ((unsigned)(a.z & 3) << 4) | ((unsigned)(a.w & 3) << 6)  |
        ((unsigned)(b.x & 3) << 8) | ((unsigned)(b.y & 3) << 10) |
        ((unsigned)(b.z & 3) << 12)| ((unsigned)(b.w & 3) << 14) |
        ((unsigned)(c.x & 3) << 16)| ((unsigned)(c.y & 3) << 18) |
        ((unsigned)(c.z & 3) << 20)| ((unsigned)(c.w & 3) << 22) |
        ((unsigned)(d.x & 3) << 24)| ((unsigned)(d.y & 3) << 26) |
        ((unsigned)(d.z & 3) << 28)| ((unsigned)(d.w & 3) << 30);
    packed[w] = v;
}

// ---------------------------------------------------------------------------
// init: species passthrough to out[0:n_species); zero the u64 accumulator.
__global__ void init_kernel(const int* __restrict__ species,
                            float* __restrict__ out,
                            unsigned long long* __restrict__ acc,
                            int n_species, int n_mol) {
    int i = blockIdx.x * blockDim.x + threadIdx.x;
    if (i < n_species) out[i] = (float)species[i];
    if (i < n_mol)     acc[i] = 0ull;
}

// ---------------------------------------------------------------------------
// Fused main kernel. LDS: exactly 80KB = 64KB packed species + 16KB u32 bins
// -> 2 blocks/CU (32 waves/CU). Table in wave registers via __shfl.
__global__ __launch_bounds__(NT, 8)
void srb_fused_u32(const unsigned* __restrict__ packed_ws,
                   const int* __restrict__ ai,     // [2, P]
                   const float* __restrict__ dist, // [P] angstrom
                   const float* __restrict__ pre_tab,   // 16 floats (negative)
                   const float* __restrict__ dfac_tab,  // 16 floats
                   unsigned long long* __restrict__ acc, // [n_mol]
                   int P, int mol_shift) {
    __shared__ unsigned packed[16384]; // 64KB: 2-bit species, all atoms
    __shared__ unsigned binsu[4096];   // 16KB: fixed-point per-mol sums

    const int t = threadIdx.x;
    for (int i = t; i < 4096; i += NT) binsu[i] = 0u;

    // register-resident table: lane L (of each wave) holds entry L&15.
    const float myPre  = -pre_tab[t & 15];   // magnitude, > 0
    const float myDfac =  dfac_tab[t & 15];

    {
        int4* dst = (int4*)packed;
        const int4* src = (const int4*)packed_ws;
        for (int i = t; i < 4096; i += NT) dst[i] = src[i];
    }
    __syncthreads();

    const float a2b   = (float)1.8897261258369282;
    const float rc    = (float)(5.2 * 1.8897261258369282);
    const float rcinv = (float)(1.0 / (5.2 * 1.8897261258369282));

    // 4 pairs per group; one-deep register prefetch pipeline.
    const int ng     = P >> 2;                 // groups of 4
    const int stride = (int)gridDim.x * NT;
    const int4*   v0 = (const int4*)ai;
    const int4*   v1 = (const int4*)(ai + P);
    const float4* dv = (const float4*)dist;

    int g = (int)blockIdx.x * NT + t;
    if (g < ng) {
        int4   A0 = v0[g];
        int4   A1 = v1[g];
        float4 D  = dv[g];

        #pragma unroll 1
        for (;;) {
            const int  gn   = g + stride;
            const bool more = (gn < ng);      // wave-uniform (ng % threads == 0)

            // ---- prefetch next group (stays in flight across the body) ----
            int4 B0, B1; float4 E;
            if (more) { B0 = v0[gn]; B1 = v1[gn]; E = dv[gn]; }

            // ---- process current group, phase-separated ----
            unsigned a0[4] = { (unsigned)A0.x, (unsigned)A0.y,
                               (unsigned)A0.z, (unsigned)A0.w };
            unsigned a1[4] = { (unsigned)A1.x, (unsigned)A1.y,
                               (unsigned)A1.z, (unsigned)A1.w };
            float    dd[4] = { D.x, D.y, D.z, D.w };

            // Phase 1: all 8 species gathers in flight.
            unsigned w0[4], w1[4];
            #pragma unroll
            for (int k = 0; k < 4; ++k) w0[k] = packed[a0[k] >> 4];
            #pragma unroll
            for (int k = 0; k < 4; ++k) w1[k] = packed[a1[k] >> 4];

            // Phase 2: table lookup via wave shuffle (ds_bpermute).
            float pr[4], df[4];
            #pragma unroll
            for (int k = 0; k < 4; ++k) {
                unsigned s0 = (w0[k] >> ((a0[k] & 15u) << 1)) & 3u;
                unsigned s1 = (w1[k] >> ((a1[k] & 15u) << 1)) & 3u;
                int idx = (int)((s0 << 2) | s1);
                pr[k] = __shfl(myPre,  idx, 64);
                df[k] = __shfl(myDfac, idx, 64);
            }

            // Phase 3: 4 independent VALU chains (bit-identical to R6).
            unsigned q[4];
            #pragma unroll
            for (int k = 0; k < 4; ++k) {
                float db  = dd[k] * a2b;
                float x   = db * rcinv;
                float arg = df[k] * db + (1.0f - 1.0f / (1.0f - x * x));
                float mag = pr[k] * __expf(arg);     // pr = |pre| > 0
                mag = (db < rc) ? mag : 0.0f;        // exact 0 beyond cutoff
                q[k] = (unsigned)(mag * SCALE_F);    // trunc; < 2^24 always
            }

            // Phase 4: 4 branchless atomics.
            #pragma unroll
            for (int k = 0; k < 4; ++k)
                atomicAdd(&binsu[a0[k] >> mol_shift], q[k]); // ds_add_u32

            if (!more) break;
            A0 = B0; A1 = B1; D = E;   // retire prefetch into current
            g  = gn;
        }
    }

    __syncthreads();
    for (int i = t; i < 4096; i += NT) {
        unsigned v = binsu[i];
        if (v) atomicAdd(&acc[i], (unsigned long long)v); // native u64 atomic
    }
}

// ---------------------------------------------------------------------------
// final: out_e[m] = energies[m] - acc[m] * 2^-27  (exact in double)
__global__ void final_kernel(const unsigned long long* __restrict__ acc,
                             const float* __restrict__ energies,
                             float* __restrict__ out_e, int n_mol) {
    int m = blockIdx.x * blockDim.x + threadIdx.x;
    if (m < n_mol)
        out_e[m] = energies[m] - (float)((double)acc[m] * INV_SCALE);
}

// ---------------------------------------------------------------------------
// Fallback (ws too small): fused float-atomic path, out_e preset.
__global__ void init_out_fallback(const int* __restrict__ species,
                                  const float* __restrict__ energies,
                                  float* __restrict__ out,
                                  int n_species, int n_mol) {
    int i = blockIdx.x * blockDim.x + threadIdx.x;
    if (i < n_species) out[i] = (float)species[i];
    else if (i < n_species + n_mol) out[i] = energies[i - n_species];
}

__global__ __launch_bounds__(NT, 1)
void srb_fused_f32(const int* __restrict__ species,
                   const int* __restrict__ ai,
                   const float* __restrict__ dist,
                   const float* __restrict__ pre_tab,
                   const float* __restrict__ dfac_tab,
                   float* __restrict__ out_e,
                   int P, int mol_shift) {
    __shared__ unsigned packed[16384];
    __shared__ float bins[4096];
    __shared__ float2 tab[16];
    const int t = threadIdx.x;
    for (int i = t; i < 4096; i += NT) bins[i] = 0.0f;
    if (t < 16) tab[t] = make_float2(pre_tab[t], dfac_tab[t]);
    for (int w = t; w < 16384; w += NT) {
        const int4* p4 = (const int4*)(species + (w << 4));
        int4 a = p4[0], b = p4[1], c = p4[2], d = p4[3];
        unsigned v =
            (unsigned)(a.x & 3)        | ((unsigned)(a.y & 3) << 2)  |
            ((unsigned)(a.z & 3) << 4) | ((unsigned)(a.w & 3) << 6)  |
            ((unsigned)(b.x & 3) << 8) | ((unsigned)(b.y & 3) << 10) |
            ((unsigned)(b.z & 3) << 12)| ((unsigned)(b.w & 3) << 14) |
            ((unsigned)(c.x & 3) << 16)| ((unsigned)(c.y & 3) << 18) |
            ((unsigned)(c.z & 3) << 20)| ((unsigned)(c.w & 3) << 22) |
            ((unsigned)(d.x & 3) << 24)| ((unsigned)(d.y & 3) << 26) |
            ((unsigned)(d.z & 3) << 28)| ((unsigned)(d.w & 3) << 30);
        packed[w] = v;
    }
    __syncthreads();
    const float a2b   = (float)1.8897261258369282;
    const float rc    = (float)(5.2 * 1.8897261258369282);
    const float rcinv = (float)(1.0 / (5.2 * 1.8897261258369282));
    auto body = [&](int a0, int a1, float dang) {
        unsigned ua0 = (unsigned)a0, ua1 = (unsigned)a1;
        unsigned s0 = (packed[ua0 >> 4] >> ((ua0 & 15u) << 1)) & 3u;
        unsigned s1 = (packed[ua1 >> 4] >> ((ua1 & 15u) << 1)) & 3u;
        float2 td = tab[(s0 << 2) | s1];
        float db = dang * a2b;
        float x  = db * rcinv;
        float arg = td.y * db + (1.0f - 1.0f / (1.0f - x * x));
        float srb = td.x * __expf(arg);
        srb = (db < rc) ? srb : 0.0f;
        atomicAdd(&bins[ua0 >> mol_shift], srb);
    };
    const int nv = P >> 2, stride = (int)gridDim.x * NT;
    const int4* v0 = (const int4*)ai;
    const int4* v1 = (const int4*)(ai + P);
    const float4* dv = (const float4*)dist;
    for (int v = (int)blockIdx.x * NT + t; v < nv; v += stride) {
        int4 i0 = v0[v]; int4 i1 = v1[v]; float4 dd = dv[v];
        body(i0.x, i1.x, dd.x); body(i0.y, i1.y, dd.y);
        body(i0.z, i1.z, dd.z); body(i0.w, i1.w, dd.w);
    }
    __syncthreads();
    for (int i = t; i < 4096; i += NT) {
        float s = bins[i];
        if (s != 0.0f) atomicAdd(&out_e[i], s);
    }
}

// ---------------------------------------------------------------------------
extern "C" void kernel_launch(void* const* d_in, const int* in_sizes, int n_in,
                              void* d_out, int out_size, void* d_ws, size_t ws_size,
                              hipStream_t stream) {
    const int*   species  = (const int*)d_in[0];
    const float* energies = (const float*)d_in[1];
    const int*   ai       = (const int*)d_in[2];
    const float* dist     = (const float*)d_in[3];
    const float* pre_tab  = (const float*)d_in[4];
    const float* dfac_tab = (const float*)d_in[5];

    const int n_species = in_sizes[0];            // 262144
    const int n_mol     = in_sizes[1];            // 4096
    const int P         = in_sizes[3];            // 16777216
    const int n_atoms   = n_species / n_mol;      // 64

    int mol_shift = 0;
    while ((1 << mol_shift) < n_atoms) ++mol_shift; // 6

    float* out   = (float*)d_out;
    float* out_e = out + n_species;

    const int    nwords    = n_species / 16;              // 16384
    const size_t packed_sz = (size_t)nwords * 4;          // 64KB
    const size_t acc_sz    = (size_t)n_mol * 8;           // 32KB
    const size_t need      = packed_sz + acc_sz;

    if (ws_size >= need && (P & 3) == 0) {
        unsigned*           packed = (unsigned*)d_ws;
        unsigned long long* acc    = (unsigned long long*)((char*)d_ws + packed_sz);

        init_kernel<<<(n_species + 255) / 256, 256, 0, stream>>>(
            species, out, acc, n_species, n_mol);
        pack_species_kernel<<<(nwords + 255) / 256, 256, 0, stream>>>(
            species, packed, nwords);
        srb_fused_u32<<<NBLK, NT, 0, stream>>>(
            packed, ai, dist, pre_tab, dfac_tab, acc, P, mol_shift);
        final_kernel<<<(n_mol + 255) / 256, 256, 0, stream>>>(
            acc, energies, out_e, n_mol);
    } else {
        init_out_fallback<<<(n_species + n_mol + 255) / 256, 256, 0, stream>>>(
            species, energies, out, n_species, n_mol);
        srb_fused_f32<<<NBLK, NT, 0, stream>>>(
            species, ai, dist, pre_tab, dfac_tab, out_e, P, mol_shift);
    }
}